// Round 1
// baseline (2419.003 us; speedup 1.0000x reference)
//
#include <hip/hip_runtime.h>
#include <math.h>

// ---------------------------------------------------------------------------
// IPOT on MI355X.
// Math restructuring:
//   T_t = M_{t-1} o (a_t b_t^T),  M_t = exp(-(t+1) C)   (elementwise)
//   row phase:  r_i = sum_j M_t(i,j) s_j ;       a_{t+1} = 1/(n r)
//   col phase:  c_j = sum_i M_t(i,j) a_{t+1}(i); b_{t+1} = 1/c          (2^10 inj)
//               s_{t+1} = b_{t+1}^2 / b_t * (1/1024)                    (2^-10 inj)
//   injections cancel: true a*b = a_hat*b_hat/1024 (applied once at the end).
// Final: G(A,B) = (1/256) sum_k P(k,A) R(k,B),
//   P(k,A)= sum_{i in A} C(k,i),  R(k,B)= a_k sum_{j in B} M_49(k,j) b_j.
// C is computed once (fp32 vector GEMM) and held in LDS by a persistent
// kernel (128 WGs x 8 rows x 4KB = 32KB/WG); 100 reduce-broadcast rounds are
// done with a 2-level tree barrier (16 group counters + 1 root).
// Workspace requirement: ~6.9 MB.
// ---------------------------------------------------------------------------

#define NWG 128
#define RPW 8   // rows of C per workgroup
#define CPW 8   // cols owned per workgroup
#define TPB 256
#define NIT 50

// ws offsets in floats
constexpr int CL_OFF    = 0;                       // -C  [1024*1024]
constexpr int S_OFF     = 1024 * 1024;             // s_hat [1024]
constexpr int BV_OFF    = S_OFF + 1024;            // b_hat [1024]
constexpr int PART_OFF  = BV_OFF + 1024;           // col partials [128][1024]
constexpr int INVX_OFF  = PART_OFF + NWG * 1024;   // [1024]
constexpr int INVY_OFF  = INVX_OFF + 1024;         // [1024]
constexpr int GPART_OFF = INVY_OFF + 1024;         // [128][4096]
constexpr int CNT_OFF   = GPART_OFF + NWG * 4096;  // 16 group ctrs + root (+pad to 32)
constexpr int TRACE_OFF = CNT_OFF + 32;            // 1 float
// total = TRACE_OFF + 1 floats ~ 6.84 MB

// --------------------------- row L2 norms ----------------------------------
__global__ __launch_bounds__(256) void k_norms(const float* __restrict__ X,
                                               const float* __restrict__ Y,
                                               float* __restrict__ ws) {
    int row  = blockIdx.x * 4 + (threadIdx.x >> 6);
    int lane = threadIdx.x & 63;
    const float* src = (row < 1024) ? (X + (size_t)row * 512)
                                    : (Y + (size_t)(row - 1024) * 512);
    float4 a = *(const float4*)(src + lane * 4);
    float4 b = *(const float4*)(src + 256 + lane * 4);
    float ss = a.x * a.x + a.y * a.y + a.z * a.z + a.w * a.w +
               b.x * b.x + b.y * b.y + b.z * b.z + b.w * b.w;
#pragma unroll
    for (int m = 1; m < 64; m <<= 1) ss += __shfl_xor(ss, m, 64);
    if (lane == 0) {
        float inv = 1.0f / sqrtf(ss);
        if (row < 1024) ws[INVX_OFF + row] = inv;
        else            ws[INVY_OFF + row - 1024] = inv;
    }
}

// ------------------- C = 1 - xhat yhat^T ; store Cl = -C --------------------
__global__ __launch_bounds__(256) void k_gemm(const float* __restrict__ X,
                                              const float* __restrict__ Y,
                                              float* __restrict__ ws) {
    __shared__ float As[32][68];  // [k][row], pad 68 keeps float4 align + no conflicts
    __shared__ float Bs[32][68];
    const float* invx = ws + INVX_OFF;
    const float* invy = ws + INVY_OFF;
    float* Cl = ws + CL_OFF;

    int tid = threadIdx.x;
    int tx = tid & 15, ty = tid >> 4;
    int bx = blockIdx.x, by = blockIdx.y;
    int lr0 = tid >> 3;          // 0..31
    int kq  = (tid & 7) * 4;     // 0..28

    float acc[4][4] = {};
    for (int k0 = 0; k0 < 512; k0 += 32) {
#pragma unroll
        for (int h = 0; h < 2; ++h) {
            int r = lr0 + h * 32;
            float4 xa = *(const float4*)(X + (size_t)(by * 64 + r) * 512 + k0 + kq);
            float4 yb = *(const float4*)(Y + (size_t)(bx * 64 + r) * 512 + k0 + kq);
            As[kq + 0][r] = xa.x; As[kq + 1][r] = xa.y;
            As[kq + 2][r] = xa.z; As[kq + 3][r] = xa.w;
            Bs[kq + 0][r] = yb.x; Bs[kq + 1][r] = yb.y;
            Bs[kq + 2][r] = yb.z; Bs[kq + 3][r] = yb.w;
        }
        __syncthreads();
#pragma unroll
        for (int kk = 0; kk < 32; ++kk) {
            float4 a4 = *(const float4*)&As[kk][4 * ty];
            float4 b4 = *(const float4*)&Bs[kk][4 * tx];
            float av[4] = {a4.x, a4.y, a4.z, a4.w};
            float bv[4] = {b4.x, b4.y, b4.z, b4.w};
#pragma unroll
            for (int r = 0; r < 4; ++r)
#pragma unroll
                for (int q = 0; q < 4; ++q) acc[r][q] += av[r] * bv[q];
        }
        __syncthreads();
    }
    int i0 = by * 64 + 4 * ty, j0 = bx * 64 + 4 * tx;
    float4 vy = *(const float4*)(invy + j0);
#pragma unroll
    for (int r = 0; r < 4; ++r) {
        float vx = invx[i0 + r];
        float4 o;
        o.x = acc[r][0] * vx * vy.x - 1.0f;   // Cl = dot - 1 = -C
        o.y = acc[r][1] * vx * vy.y - 1.0f;
        o.z = acc[r][2] * vx * vy.z - 1.0f;
        o.w = acc[r][3] * vx * vy.w - 1.0f;
        *(float4*)(Cl + (size_t)(i0 + r) * 1024 + j0) = o;
    }
}

// --------------------------- tree barrier ----------------------------------
__device__ __forceinline__ void gridbar(unsigned* grp, unsigned* root, int g,
                                        unsigned epoch) {
    __syncthreads();
    __threadfence();  // release: make this WG's global writes device-visible
    if (threadIdx.x == 0) {
        int gid = g >> 3;  // 16 groups of 8
        unsigned tgt = epoch * 8u;
        unsigned old = atomicAdd(&grp[gid], 1u);
        if (old == tgt - 1u) atomicAdd(root, 1u);  // last of group promotes
        unsigned rt = epoch * 16u;
        int guard = 0;
        while (__hip_atomic_load(root, __ATOMIC_RELAXED,
                                 __HIP_MEMORY_SCOPE_AGENT) < rt) {
            __builtin_amdgcn_s_sleep(2);
            if (++guard > 4000000) break;  // anti-hang bailout (~0.3s)
        }
    }
    __syncthreads();
    __threadfence();  // acquire: invalidate stale cached globals
}

// ---------------------- persistent IPOT iteration --------------------------
__global__ __launch_bounds__(256) void k_ipot(float* __restrict__ ws) {
    __shared__ float Ct[RPW * 1024];   // this WG's 8 rows of Cl (= -C)
    __shared__ float vec[1024];        // staged s_hat (loop) / b_hat (epilogue)
    __shared__ float aL[RPW];
    __shared__ float bOwn[CPW];
    __shared__ float red[CPW][33];
    __shared__ float Ps[RPW][64];
    __shared__ float Rs[RPW][64];

    const int g = blockIdx.x, tid = threadIdx.x;
    float* Cl   = ws + CL_OFF;
    float* svec = ws + S_OFF;
    float* bvec = ws + BV_OFF;
    float* part = ws + PART_OFF;
    unsigned* grp  = (unsigned*)(ws + CNT_OFF);
    unsigned* root = grp + 16;

    {   // C rows -> LDS (read from HBM exactly once)
        const float* src = Cl + (size_t)g * RPW * 1024;
        for (int o = tid * 4; o < RPW * 1024; o += TPB * 4)
            *(float4*)(Ct + o) = *(const float4*)(src + o);
    }
    if (tid < CPW) bOwn[tid] = 1.0f;

    const int wv = tid >> 6, lane = tid & 63;
    unsigned ep = 0;

    for (int t = 0; t < NIT; ++t) {
        if (t == 0) {
            for (int o = tid; o < 1024; o += TPB) vec[o] = 1.0f / 1024.0f;
        } else {
            for (int o = tid * 4; o < 1024; o += TPB * 4)
                *(float4*)(vec + o) = *(const float4*)(svec + o);
        }
        __syncthreads();
        const float kf = (float)(t + 1);

        // row phase: r_i = sum_j exp(kf*Cl) * s ; a = 1/(n r)
#pragma unroll
        for (int rr = 0; rr < 2; ++rr) {
            int i = wv * 2 + rr;
            const float* crow = Ct + i * 1024;
            float acc = 0.0f;
#pragma unroll
            for (int c = 0; c < 16; ++c) {
                int j = lane + 64 * c;
                acc += __expf(kf * crow[j]) * vec[j];
            }
#pragma unroll
            for (int m = 1; m < 64; m <<= 1) acc += __shfl_xor(acc, m, 64);
            if (lane == 0) aL[i] = 1.0f / (1024.0f * acc);
        }
        __syncthreads();

        // col partials over local rows: p_j = sum_i M(i,j) a_i
        {
            int j4 = tid * 4;
            float4 p = {0.0f, 0.0f, 0.0f, 0.0f};
#pragma unroll
            for (int i = 0; i < RPW; ++i) {
                float ai = aL[i];
                float4 c4 = *(const float4*)(Ct + i * 1024 + j4);
                p.x += __expf(kf * c4.x) * ai;
                p.y += __expf(kf * c4.y) * ai;
                p.z += __expf(kf * c4.z) * ai;
                p.w += __expf(kf * c4.w) * ai;
            }
            *(float4*)(part + (size_t)g * 1024 + j4) = p;
        }
        gridbar(grp, root, g, ++ep);

        // col phase: reduce 128 partials for our 8 owned cols
        {
            int jl = tid & 7, pg = tid >> 3;  // pg 0..31
            int jcol = g * CPW + jl;
            float s = 0.0f;
#pragma unroll
            for (int q = 0; q < 4; ++q)
                s += part[(size_t)(4 * pg + q) * 1024 + jcol];
            red[jl][pg] = s;
        }
        __syncthreads();
        if (tid < CPW) {
            float c = 0.0f;
#pragma unroll
            for (int pg = 0; pg < 32; ++pg) c += red[tid][pg];
            float bn = 1.0f / c;                                // 2^10 injection
            float sn = bn * bn / bOwn[tid] * (1.0f / 1024.0f);  // 2^-10 injection
            bOwn[tid] = bn;
            svec[g * CPW + tid] = sn;
            bvec[g * CPW + tid] = bn;
        }
        gridbar(grp, root, g, ++ep);
    }

    // epilogue: G_partial(A,B) = sum_{local k} P(k,A) R(k,B)
    for (int o = tid * 4; o < 1024; o += TPB * 4)
        *(float4*)(vec + o) = *(const float4*)(bvec + o);
    __syncthreads();
    for (int id = tid; id < RPW * 64; id += TPB) {
        int i = id >> 6, A = id & 63;
        const float* crow = Ct + i * 1024 + A * 16;
        float sc = 0.0f, sr = 0.0f;
#pragma unroll
        for (int q = 0; q < 16; ++q) {
            float cl = crow[q];
            sc += cl;
            sr += __expf(50.0f * cl) * vec[A * 16 + q];
        }
        Ps[i][A] = -sc;            // C = -Cl
        Rs[i][A] = aL[i] * sr;
    }
    __syncthreads();
    {
        float* gp = ws + GPART_OFF + (size_t)g * 4096;
#pragma unroll
        for (int q = 0; q < 16; ++q) {
            int o = tid + 256 * q;
            int A = o >> 6, B = o & 63;
            float acc = 0.0f;
#pragma unroll
            for (int k = 0; k < RPW; ++k) acc += Ps[k][A] * Rs[k][B];
            gp[o] = acc;
        }
    }
}

// ----------------- reduce per-WG G partials, trace -------------------------
__global__ __launch_bounds__(256) void k_reduce(float* __restrict__ ws,
                                                float* __restrict__ out) {
    int o = blockIdx.x * 256 + threadIdx.x;  // 16 blocks x 256 = 4096
    const float* gp = ws + GPART_OFF;
    float acc = 0.0f;
    for (int g = 0; g < NWG; ++g) acc += gp[(size_t)g * 4096 + o];
    // 1/256 block mean, 1/1024 from the a*b exponent-injection reconstruction
    float val = acc * (1.0f / (256.0f * 1024.0f));
    out[o] = val;
    if ((o >> 6) == (o & 63)) atomicAdd(ws + TRACE_OFF, val);
}

__global__ void k_trace(const float* __restrict__ ws, float* __restrict__ out) {
    if (threadIdx.x == 0) out[4096] = ws[TRACE_OFF];
}

// ---------------------------------------------------------------------------
extern "C" void kernel_launch(void* const* d_in, const int* in_sizes, int n_in,
                              void* d_out, int out_size, void* d_ws, size_t ws_size,
                              hipStream_t stream) {
    const float* X = (const float*)d_in[0];  // t_prob [1024,512]
    const float* Y = (const float*)d_in[1];  // v_prob [1024,512]
    float* out = (float*)d_out;              // [64*64 + 1]
    float* ws  = (float*)d_ws;               // needs ~6.9 MB

    // zero barrier counters + trace accumulator (ws is poisoned 0xAA each call)
    hipMemsetAsync((char*)d_ws + (size_t)CNT_OFF * 4, 0, 33 * 4, stream);

    k_norms<<<512, 256, 0, stream>>>(X, Y, ws);
    k_gemm<<<dim3(16, 16), 256, 0, stream>>>(X, Y, ws);
    k_ipot<<<NWG, TPB, 0, stream>>>(ws);
    k_reduce<<<16, 256, 0, stream>>>(ws, out);
    k_trace<<<1, 64, 0, stream>>>(ws, out);
}

// Round 2
// 516.968 us; speedup vs baseline: 4.6792x; 4.6792x over previous
//
#include <hip/hip_runtime.h>
#include <math.h>

// ---------------------------------------------------------------------------
// IPOT on MI355X — round 2.
// Same math as R1 (exact, absmax 0.0):
//   Cl = -C;  M_t = exp((t+1)*Cl)
//   row:  r_i = sum_j M_t(i,j) s_j ; a = 1/(n r)          (per row-owner WG)
//   col:  c_j = sum_i M_t(i,j) a_i ; b = 1/c (2^10 inj);  s' = b^2/b_prev/1024
//   final G(A,B) = (1/(256*1024)) sum_k P(k,A) R(k,B)
// R2 changes (kill the 23.5us/round fence storm):
//   - NO __threadfence anywhere. All cross-WG data moves via device-scope
//     atomics (cache-bypassing): atomicAdd accumulate into cvec, relaxed
//     agent-scope atomic loads to read it back.
//   - ONE grid barrier per iteration (was 2): every WG redundantly computes
//     b/s for ALL 1024 columns from cvec (full b,s state lives in LDS).
//   - cvec: 4 replicas (cap same-address RMW chain at 32) x 3 rotating
//     buffers (zeroing window separated from adds/reads by 2 barriers).
//   - barrier: 2-level tree, relaxed atomics; __syncthreads' vmcnt(0) drain
//     orders the data atomics before the arrival.
// ---------------------------------------------------------------------------

#define NWG 128
#define RPW 8   // C rows per WG
#define TPB 256
#define NIT 50
#define NREP 4  // cvec replicas

// ws offsets in floats
constexpr int CL_OFF    = 0;                         // -C [1024*1024]
constexpr int INVX_OFF  = 1024 * 1024;               // [1024]
constexpr int INVY_OFF  = INVX_OFF + 1024;           // [1024]
constexpr int GPART_OFF = INVY_OFF + 1024;           // [128][4096]
constexpr int CVEC_OFF  = GPART_OFF + NWG * 4096;    // [3][NREP][1024]
constexpr int CNT_OFF   = CVEC_OFF + 3 * NREP * 1024;// 16 grp + root + pad(32)
constexpr int TRACE_OFF = CNT_OFF + 32;              // 1
// total ~ 6.35 MB

// --------------------------- row L2 norms ----------------------------------
__global__ __launch_bounds__(256) void k_norms(const float* __restrict__ X,
                                               const float* __restrict__ Y,
                                               float* __restrict__ ws) {
    int row  = blockIdx.x * 4 + (threadIdx.x >> 6);
    int lane = threadIdx.x & 63;
    const float* src = (row < 1024) ? (X + (size_t)row * 512)
                                    : (Y + (size_t)(row - 1024) * 512);
    float4 a = *(const float4*)(src + lane * 4);
    float4 b = *(const float4*)(src + 256 + lane * 4);
    float ss = a.x * a.x + a.y * a.y + a.z * a.z + a.w * a.w +
               b.x * b.x + b.y * b.y + b.z * b.z + b.w * b.w;
#pragma unroll
    for (int m = 1; m < 64; m <<= 1) ss += __shfl_xor(ss, m, 64);
    if (lane == 0) {
        float inv = 1.0f / sqrtf(ss);
        if (row < 1024) ws[INVX_OFF + row] = inv;
        else            ws[INVY_OFF + row - 1024] = inv;
    }
}

// ------------------- C = 1 - xhat yhat^T ; store Cl = -C --------------------
__global__ __launch_bounds__(256) void k_gemm(const float* __restrict__ X,
                                              const float* __restrict__ Y,
                                              float* __restrict__ ws) {
    __shared__ float As[32][68];
    __shared__ float Bs[32][68];
    const float* invx = ws + INVX_OFF;
    const float* invy = ws + INVY_OFF;
    float* Cl = ws + CL_OFF;

    int tid = threadIdx.x;
    int tx = tid & 15, ty = tid >> 4;
    int bx = blockIdx.x, by = blockIdx.y;
    int lr0 = tid >> 3;
    int kq  = (tid & 7) * 4;

    float acc[4][4] = {};
    for (int k0 = 0; k0 < 512; k0 += 32) {
#pragma unroll
        for (int h = 0; h < 2; ++h) {
            int r = lr0 + h * 32;
            float4 xa = *(const float4*)(X + (size_t)(by * 64 + r) * 512 + k0 + kq);
            float4 yb = *(const float4*)(Y + (size_t)(bx * 64 + r) * 512 + k0 + kq);
            As[kq + 0][r] = xa.x; As[kq + 1][r] = xa.y;
            As[kq + 2][r] = xa.z; As[kq + 3][r] = xa.w;
            Bs[kq + 0][r] = yb.x; Bs[kq + 1][r] = yb.y;
            Bs[kq + 2][r] = yb.z; Bs[kq + 3][r] = yb.w;
        }
        __syncthreads();
#pragma unroll
        for (int kk = 0; kk < 32; ++kk) {
            float4 a4 = *(const float4*)&As[kk][4 * ty];
            float4 b4 = *(const float4*)&Bs[kk][4 * tx];
            float av[4] = {a4.x, a4.y, a4.z, a4.w};
            float bv[4] = {b4.x, b4.y, b4.z, b4.w};
#pragma unroll
            for (int r = 0; r < 4; ++r)
#pragma unroll
                for (int q = 0; q < 4; ++q) acc[r][q] += av[r] * bv[q];
        }
        __syncthreads();
    }
    int i0 = by * 64 + 4 * ty, j0 = bx * 64 + 4 * tx;
    float4 vy = *(const float4*)(invy + j0);
#pragma unroll
    for (int r = 0; r < 4; ++r) {
        float vx = invx[i0 + r];
        float4 o;
        o.x = acc[r][0] * vx * vy.x - 1.0f;
        o.y = acc[r][1] * vx * vy.y - 1.0f;
        o.z = acc[r][2] * vx * vy.z - 1.0f;
        o.w = acc[r][3] * vx * vy.w - 1.0f;
        *(float4*)(Cl + (size_t)(i0 + r) * 1024 + j0) = o;
    }
}

// ------------------- fence-free tree barrier (relaxed) ----------------------
__device__ __forceinline__ void gridbar(unsigned* grp, unsigned* root, int g,
                                        unsigned epoch) {
    // __syncthreads lowers to s_waitcnt vmcnt(0) lgkmcnt(0) + s_barrier:
    // all this WG's data atomics are complete before tid0 arrives.
    __syncthreads();
    if (threadIdx.x == 0) {
        int gid = g >> 3;  // 16 groups of 8
        unsigned tgt = epoch * 8u;
        unsigned old = __hip_atomic_fetch_add(&grp[gid], 1u, __ATOMIC_RELAXED,
                                              __HIP_MEMORY_SCOPE_AGENT);
        if (old == tgt - 1u)
            __hip_atomic_fetch_add(root, 1u, __ATOMIC_RELAXED,
                                   __HIP_MEMORY_SCOPE_AGENT);
        unsigned rt = epoch * 16u;
        long guard = 0;
        while (__hip_atomic_load(root, __ATOMIC_RELAXED,
                                 __HIP_MEMORY_SCOPE_AGENT) < rt) {
            __builtin_amdgcn_s_sleep(2);
            if (++guard > 3000000) break;  // anti-hang bailout
        }
    }
    __syncthreads();
}

// ---------------------- persistent IPOT iteration --------------------------
__global__ __launch_bounds__(256) void k_ipot(float* __restrict__ ws) {
    __shared__ float Ct[RPW * 1024];  // 32 KB: this WG's rows of Cl
    __shared__ float sArr[1024];      // full s_hat (redundant per WG)
    __shared__ float bArr[1024];      // full b_hat (redundant per WG)
    __shared__ float aL[RPW];
    __shared__ float Ps[RPW * 64];
    __shared__ float Rs[RPW * 64];

    const int g = blockIdx.x, tid = threadIdx.x;
    float* Cl   = ws + CL_OFF;
    float* cvec = ws + CVEC_OFF;
    unsigned* grp  = (unsigned*)(ws + CNT_OFF);
    unsigned* root = grp + 16;

    {   // C rows -> LDS once
        const float* src = Cl + (size_t)g * RPW * 1024;
        for (int o = tid * 4; o < RPW * 1024; o += TPB * 4)
            *(float4*)(Ct + o) = *(const float4*)(src + o);
    }
    for (int o = tid; o < 1024; o += TPB) bArr[o] = 1.0f;

    const int wv = tid >> 6, lane = tid & 63;
    unsigned ep = 0;

    for (int t = 0; t < NIT; ++t) {
        if (t == 0) {
            for (int o = tid; o < 1024; o += TPB) sArr[o] = 1.0f / 1024.0f;
        } else {
            // col update for ALL columns from cvec (bypass loads)
            const float* rb = cvec + ((t - 1) % 3) * NREP * 1024;
            int j0 = tid * 4;
#pragma unroll
            for (int u = 0; u < 4; ++u) {
                int j = j0 + u;
                float c = 0.0f;
#pragma unroll
                for (int r = 0; r < NREP; ++r)
                    c += __hip_atomic_load(rb + r * 1024 + j, __ATOMIC_RELAXED,
                                           __HIP_MEMORY_SCOPE_AGENT);
                float bn = 1.0f / c;                                 // 2^10 inj
                float sn = bn * bn / bArr[j] * (1.0f / 1024.0f);     // 2^-10 inj
                bArr[j] = bn;
                sArr[j] = sn;
            }
            if (t >= 2 && tid < 32) {   // zero buffer used 2 iters ago
                float* zb = cvec + ((t - 2) % 3) * NREP * 1024;
                __hip_atomic_store(zb + g * 32 + tid, 0.0f, __ATOMIC_RELAXED,
                                   __HIP_MEMORY_SCOPE_AGENT);
            }
        }
        __syncthreads();
        const float kf = (float)(t + 1);

        // row phase: a_i for local rows
#pragma unroll
        for (int rr = 0; rr < 2; ++rr) {
            int i = wv * 2 + rr;
            const float* crow = Ct + i * 1024;
            float acc = 0.0f;
#pragma unroll
            for (int c = 0; c < 16; ++c) {
                int j = lane + 64 * c;
                acc += __expf(kf * crow[j]) * sArr[j];
            }
#pragma unroll
            for (int m = 1; m < 64; m <<= 1) acc += __shfl_xor(acc, m, 64);
            if (lane == 0) aL[i] = 1.0f / (1024.0f * acc);
        }
        __syncthreads();

        // col partials over local rows -> atomicAdd into replica g&3
        {
            float* wb = cvec + (t % 3) * NREP * 1024 + (g & (NREP - 1)) * 1024;
            int j4 = tid * 4;
            float4 p = {0.0f, 0.0f, 0.0f, 0.0f};
#pragma unroll
            for (int i = 0; i < RPW; ++i) {
                float ai = aL[i];
                float4 c4 = *(const float4*)(Ct + i * 1024 + j4);
                p.x += __expf(kf * c4.x) * ai;
                p.y += __expf(kf * c4.y) * ai;
                p.z += __expf(kf * c4.z) * ai;
                p.w += __expf(kf * c4.w) * ai;
            }
            atomicAdd(wb + j4 + 0, p.x);
            atomicAdd(wb + j4 + 1, p.y);
            atomicAdd(wb + j4 + 2, p.z);
            atomicAdd(wb + j4 + 3, p.w);
        }
        gridbar(grp, root, g, ++ep);
    }

    // final b from last buffer
    {
        const float* rb = cvec + ((NIT - 1) % 3) * NREP * 1024;
        int j0 = tid * 4;
#pragma unroll
        for (int u = 0; u < 4; ++u) {
            int j = j0 + u;
            float c = 0.0f;
#pragma unroll
            for (int r = 0; r < NREP; ++r)
                c += __hip_atomic_load(rb + r * 1024 + j, __ATOMIC_RELAXED,
                                       __HIP_MEMORY_SCOPE_AGENT);
            bArr[j] = 1.0f / c;
        }
    }
    __syncthreads();

    // epilogue: P(k,A), R(k,B) then gpart(A,B) = sum_k P R
    for (int id = tid; id < RPW * 64; id += TPB) {
        int i = id >> 6, A = id & 63;
        const float* crow = Ct + i * 1024 + A * 16;
        float sc = 0.0f, sr = 0.0f;
#pragma unroll
        for (int q = 0; q < 16; ++q) {
            float cl = crow[q];
            sc += cl;
            sr += __expf(50.0f * cl) * bArr[A * 16 + q];
        }
        Ps[id] = -sc;          // C = -Cl
        Rs[id] = aL[i] * sr;
    }
    __syncthreads();
    {
        float* gp = ws + GPART_OFF + (size_t)g * 4096;
#pragma unroll
        for (int q = 0; q < 16; ++q) {
            int o = tid + 256 * q;
            int A = o >> 6, B = o & 63;
            float acc = 0.0f;
#pragma unroll
            for (int k = 0; k < RPW; ++k) acc += Ps[k * 64 + A] * Rs[k * 64 + B];
            gp[o] = acc;
        }
    }
}

// ----------------- reduce per-WG G partials, trace -------------------------
__global__ __launch_bounds__(256) void k_reduce(float* __restrict__ ws,
                                                float* __restrict__ out) {
    int o = blockIdx.x * 256 + threadIdx.x;  // 16 x 256 = 4096
    const float* gp = ws + GPART_OFF;
    float acc = 0.0f;
    for (int g = 0; g < NWG; ++g) acc += gp[(size_t)g * 4096 + o];
    float val = acc * (1.0f / (256.0f * 1024.0f));
    out[o] = val;
    if ((o >> 6) == (o & 63)) atomicAdd(ws + TRACE_OFF, val);
}

__global__ void k_trace(const float* __restrict__ ws, float* __restrict__ out) {
    if (threadIdx.x == 0) out[4096] = ws[TRACE_OFF];
}

// ---------------------------------------------------------------------------
extern "C" void kernel_launch(void* const* d_in, const int* in_sizes, int n_in,
                              void* d_out, int out_size, void* d_ws, size_t ws_size,
                              hipStream_t stream) {
    const float* X = (const float*)d_in[0];
    const float* Y = (const float*)d_in[1];
    float* out = (float*)d_out;
    float* ws  = (float*)d_ws;

    // zero cvec buffers + barrier counters + trace (ws poisoned each call)
    hipMemsetAsync((char*)d_ws + (size_t)CVEC_OFF * 4, 0,
                   (3 * NREP * 1024 + 33) * 4, stream);

    k_norms<<<512, 256, 0, stream>>>(X, Y, ws);
    k_gemm<<<dim3(16, 16), 256, 0, stream>>>(X, Y, ws);
    k_ipot<<<NWG, TPB, 0, stream>>>(ws);
    k_reduce<<<16, 256, 0, stream>>>(ws, out);
    k_trace<<<1, 64, 0, stream>>>(ws, out);
}

// Round 4
// 457.246 us; speedup vs baseline: 5.2904x; 1.1306x over previous
//
#include <hip/hip_runtime.h>
#include <math.h>

// ---------------------------------------------------------------------------
// IPOT on MI355X — round 4 (R3 design, compile fix).
// Math (exact, verified absmax 0.0 in R1/R2):
//   Cl = -C;  M_t = exp((t+1)*Cl)
//   row:  r_i = sum_j M_t(i,j) s_j ; a = 1/(n r)
//   col:  c_j = sum_i M_t(i,j) a_i ; b = 1/c (2^10 inj); s' = b^2/b_prev/1024
//   final G(A,B) = (1/(256*1024)) sum_k P(k,A) R(k,B)
// R4 = R3 with the inline-asm dwordx4 readback replaced by 8-byte
// __hip_atomic_load (compiler-managed waitcnt; no tied-operand asm):
//   - NWG=64, C in REGISTERS: thread owns C[16 rows][4 cols] (64 VGPR).
//   - E=exp(kf*C) cached in regs; col phase + epilogue reuse it.
//   - readback 4x8B coherent loads/thread issued before the exp block.
//   - ~132k LLC atomic tx/round vs R2's 655k.
//   - k_norms fused into k_gemm; final reduce+trace fused into k_ipot.
// ---------------------------------------------------------------------------

#define NWG 64
#define TPB 256
#define NIT 50
#define NREP 2

// ws offsets in floats
constexpr int CL_OFF   = 0;                          // -C [1024*1024]
constexpr int CVEC_OFF = 1024 * 1024;                // [3][NREP][1024]
constexpr int CNT_OFF  = CVEC_OFF + 3 * NREP * 1024; // 8 grp + root (pad 32)
// total ~ 4.03 MB

// ---------------- C = 1 - xhat yhat^T (norms fused) ; Cl = -C ---------------
__global__ __launch_bounds__(256) void k_gemm(const float* __restrict__ X,
                                              const float* __restrict__ Y,
                                              float* __restrict__ ws) {
    __shared__ float As[32][68];
    __shared__ float Bs[32][68];
    __shared__ float nX[64], nY[64];
    float* Cl = ws + CL_OFF;

    int tid = threadIdx.x;
    int tx = tid & 15, ty = tid >> 4;
    int bx = blockIdx.x, by = blockIdx.y;
    int lr0 = tid >> 3;          // 0..31
    int kq  = (tid & 7) * 4;     // 0..28

    float acc[4][4] = {};
    float sx0 = 0.f, sx1 = 0.f, sy0 = 0.f, sy1 = 0.f;
    for (int k0 = 0; k0 < 512; k0 += 32) {
        float4 xa = *(const float4*)(X + (size_t)(by * 64 + lr0) * 512 + k0 + kq);
        float4 xb = *(const float4*)(X + (size_t)(by * 64 + lr0 + 32) * 512 + k0 + kq);
        float4 ya = *(const float4*)(Y + (size_t)(bx * 64 + lr0) * 512 + k0 + kq);
        float4 yb = *(const float4*)(Y + (size_t)(bx * 64 + lr0 + 32) * 512 + k0 + kq);
        sx0 += xa.x * xa.x + xa.y * xa.y + xa.z * xa.z + xa.w * xa.w;
        sx1 += xb.x * xb.x + xb.y * xb.y + xb.z * xb.z + xb.w * xb.w;
        sy0 += ya.x * ya.x + ya.y * ya.y + ya.z * ya.z + ya.w * ya.w;
        sy1 += yb.x * yb.x + yb.y * yb.y + yb.z * yb.z + yb.w * yb.w;
        As[kq + 0][lr0] = xa.x; As[kq + 1][lr0] = xa.y;
        As[kq + 2][lr0] = xa.z; As[kq + 3][lr0] = xa.w;
        As[kq + 0][lr0 + 32] = xb.x; As[kq + 1][lr0 + 32] = xb.y;
        As[kq + 2][lr0 + 32] = xb.z; As[kq + 3][lr0 + 32] = xb.w;
        Bs[kq + 0][lr0] = ya.x; Bs[kq + 1][lr0] = ya.y;
        Bs[kq + 2][lr0] = ya.z; Bs[kq + 3][lr0] = ya.w;
        Bs[kq + 0][lr0 + 32] = yb.x; Bs[kq + 1][lr0 + 32] = yb.y;
        Bs[kq + 2][lr0 + 32] = yb.z; Bs[kq + 3][lr0 + 32] = yb.w;
        __syncthreads();
#pragma unroll
        for (int kk = 0; kk < 32; ++kk) {
            float4 a4 = *(const float4*)&As[kk][4 * ty];
            float4 b4 = *(const float4*)&Bs[kk][4 * tx];
            float av[4] = {a4.x, a4.y, a4.z, a4.w};
            float bv[4] = {b4.x, b4.y, b4.z, b4.w};
#pragma unroll
            for (int r = 0; r < 4; ++r)
#pragma unroll
                for (int q = 0; q < 4; ++q) acc[r][q] += av[r] * bv[q];
        }
        __syncthreads();
    }
    // row-norm reduce across the 8 staging threads of each row
#pragma unroll
    for (int m = 1; m < 8; m <<= 1) {
        sx0 += __shfl_xor(sx0, m, 64);
        sx1 += __shfl_xor(sx1, m, 64);
        sy0 += __shfl_xor(sy0, m, 64);
        sy1 += __shfl_xor(sy1, m, 64);
    }
    if ((tid & 7) == 0) {
        nX[lr0] = sx0; nX[lr0 + 32] = sx1;
        nY[lr0] = sy0; nY[lr0 + 32] = sy1;
    }
    __syncthreads();

    int i0 = by * 64 + 4 * ty, j0 = bx * 64 + 4 * tx;
    float vy[4];
#pragma unroll
    for (int q = 0; q < 4; ++q) vy[q] = 1.0f / sqrtf(nY[4 * tx + q]);
#pragma unroll
    for (int r = 0; r < 4; ++r) {
        float vx = 1.0f / sqrtf(nX[4 * ty + r]);
        float4 o;
        o.x = acc[r][0] * vx * vy[0] - 1.0f;  // Cl = dot - 1 = -C
        o.y = acc[r][1] * vx * vy[1] - 1.0f;
        o.z = acc[r][2] * vx * vy[2] - 1.0f;
        o.w = acc[r][3] * vx * vy[3] - 1.0f;
        *(float4*)(Cl + (size_t)(i0 + r) * 1024 + j0) = o;
    }
}

// ------------------- fence-free tree barrier (relaxed) ----------------------
__device__ __forceinline__ void gridbar(unsigned* grp, unsigned* root, int g,
                                        unsigned epoch) {
    __syncthreads();  // drains vmcnt(0): data atomics done before arrival
    if (threadIdx.x == 0) {
        int gid = g >> 3;  // 8 groups of 8
        unsigned tgt = epoch * 8u;
        unsigned old = __hip_atomic_fetch_add(&grp[gid], 1u, __ATOMIC_RELAXED,
                                              __HIP_MEMORY_SCOPE_AGENT);
        if (old == tgt - 1u)
            __hip_atomic_fetch_add(root, 1u, __ATOMIC_RELAXED,
                                   __HIP_MEMORY_SCOPE_AGENT);
        unsigned rt = epoch * 8u;  // 8 groups
        long guard = 0;
        while (__hip_atomic_load(root, __ATOMIC_RELAXED,
                                 __HIP_MEMORY_SCOPE_AGENT) < rt) {
            __builtin_amdgcn_s_sleep(1);
            if (++guard > 1000000) break;  // anti-hang bailout
        }
    }
    __syncthreads();
}

// ---------------------- persistent IPOT iteration --------------------------
__global__ __launch_bounds__(256, 1) void k_ipot(float* __restrict__ ws,
                                                 float* __restrict__ out) {
    __shared__ float rws[4][16];
    __shared__ float aL[16];
    __shared__ float Ps[16][64];
    __shared__ float Rs[16][64];

    const int g = blockIdx.x, tid = threadIdx.x;
    const int wv = tid >> 6, lane = tid & 63;
    float* Cl   = ws + CL_OFF;
    float* cvec = ws + CVEC_OFF;
    unsigned* grp  = (unsigned*)(ws + CNT_OFF);
    unsigned* root = grp + 8;

    // C block -> registers: thread owns rows g*16..g*16+15, cols 4*tid..4*tid+3
    float C[16][4], E[16][4];
#pragma unroll
    for (int i = 0; i < 16; ++i) {
        float4 c = *(const float4*)(Cl + (size_t)(g * 16 + i) * 1024 + 4 * tid);
        C[i][0] = c.x; C[i][1] = c.y; C[i][2] = c.z; C[i][3] = c.w;
    }
    float bv[4] = {1.0f, 1.0f, 1.0f, 1.0f};
    float s[4];
    unsigned ep = 0;

    for (int t = 0; t < NIT; ++t) {
        // issue coherent readback of prev round's col sums (8B atomic loads,
        // waitcnt lands after the exp block below -> latency hidden)
        unsigned long long u0 = 0, u1 = 0, u2 = 0, u3 = 0;
        if (t > 0) {
            const unsigned long long* p0 = (const unsigned long long*)
                (cvec + ((t + 2) % 3) * (NREP * 1024) + 4 * tid);
            const unsigned long long* p1 = (const unsigned long long*)
                (cvec + ((t + 2) % 3) * (NREP * 1024) + 1024 + 4 * tid);
            u0 = __hip_atomic_load(p0,     __ATOMIC_RELAXED, __HIP_MEMORY_SCOPE_AGENT);
            u1 = __hip_atomic_load(p0 + 1, __ATOMIC_RELAXED, __HIP_MEMORY_SCOPE_AGENT);
            u2 = __hip_atomic_load(p1,     __ATOMIC_RELAXED, __HIP_MEMORY_SCOPE_AGENT);
            u3 = __hip_atomic_load(p1 + 1, __ATOMIC_RELAXED, __HIP_MEMORY_SCOPE_AGENT);
        }
        const float kf = (float)(t + 1);
#pragma unroll
        for (int i = 0; i < 16; ++i)
#pragma unroll
            for (int u = 0; u < 4; ++u) E[i][u] = __expf(kf * C[i][u]);

        if (t == 0) {
            s[0] = s[1] = s[2] = s[3] = 1.0f / 1024.0f;
        } else {
            float c0 = __uint_as_float((unsigned)u0) + __uint_as_float((unsigned)u2);
            float c1 = __uint_as_float((unsigned)(u0 >> 32)) + __uint_as_float((unsigned)(u2 >> 32));
            float c2 = __uint_as_float((unsigned)u1) + __uint_as_float((unsigned)u3);
            float c3 = __uint_as_float((unsigned)(u1 >> 32)) + __uint_as_float((unsigned)(u3 >> 32));
            float b0 = 1.0f / c0, b1 = 1.0f / c1, b2 = 1.0f / c2, b3 = 1.0f / c3;
            s[0] = b0 * b0 / bv[0] * (1.0f / 1024.0f); bv[0] = b0;  // 2^-10 inj
            s[1] = b1 * b1 / bv[1] * (1.0f / 1024.0f); bv[1] = b1;
            s[2] = b2 * b2 / bv[2] * (1.0f / 1024.0f); bv[2] = b2;
            s[3] = b3 * b3 / bv[3] * (1.0f / 1024.0f); bv[3] = b3;
            if (t >= 2 && tid < 16) {  // zero buffer last read at round t-1
                unsigned long long* zb = (unsigned long long*)
                    (cvec + ((t + 1) % 3) * (NREP * 1024)) + g * 16 + tid;
                __hip_atomic_store(zb, 0ull, __ATOMIC_RELAXED,
                                   __HIP_MEMORY_SCOPE_AGENT);
            }
        }

        // row partials over this thread's 4 cols, then WG-wide reduce
        float rp[16];
#pragma unroll
        for (int i = 0; i < 16; ++i)
            rp[i] = E[i][0] * s[0] + E[i][1] * s[1] + E[i][2] * s[2] + E[i][3] * s[3];
#pragma unroll
        for (int m = 1; m < 64; m <<= 1)
#pragma unroll
            for (int i = 0; i < 16; ++i) rp[i] += __shfl_xor(rp[i], m, 64);
        if (lane == 0) {
#pragma unroll
            for (int i = 0; i < 16; ++i) rws[wv][i] = rp[i];
        }
        __syncthreads();
        if (tid < 16)
            aL[tid] = 1.0f / (1024.0f * (rws[0][tid] + rws[1][tid] +
                                         rws[2][tid] + rws[3][tid]));
        __syncthreads();

        // col partials for this thread's 4 cols (reuses E) -> atomicAdd
        float p0 = 0.f, p1 = 0.f, p2 = 0.f, p3 = 0.f;
#pragma unroll
        for (int i = 0; i < 16; ++i) {
            float ai = aL[i];
            p0 += E[i][0] * ai; p1 += E[i][1] * ai;
            p2 += E[i][2] * ai; p3 += E[i][3] * ai;
        }
        float* wb = cvec + (t % 3) * (NREP * 1024) + (g & 1) * 1024 + 4 * tid;
        atomicAdd(wb + 0, p0);
        atomicAdd(wb + 1, p1);
        atomicAdd(wb + 2, p2);
        atomicAdd(wb + 3, p3);

        gridbar(grp, root, g, ++ep);
    }

    // final b (round-49 col sums); E still holds exp(50*Cl)
    float bf[4];
    {
        const unsigned long long* q0 = (const unsigned long long*)
            (cvec + ((NIT - 1) % 3) * (NREP * 1024) + 4 * tid);
        const unsigned long long* q1 = (const unsigned long long*)
            (cvec + ((NIT - 1) % 3) * (NREP * 1024) + 1024 + 4 * tid);
        unsigned long long f0 = __hip_atomic_load(q0,     __ATOMIC_RELAXED, __HIP_MEMORY_SCOPE_AGENT);
        unsigned long long f1 = __hip_atomic_load(q0 + 1, __ATOMIC_RELAXED, __HIP_MEMORY_SCOPE_AGENT);
        unsigned long long f2 = __hip_atomic_load(q1,     __ATOMIC_RELAXED, __HIP_MEMORY_SCOPE_AGENT);
        unsigned long long f3 = __hip_atomic_load(q1 + 1, __ATOMIC_RELAXED, __HIP_MEMORY_SCOPE_AGENT);
        bf[0] = 1.0f / (__uint_as_float((unsigned)f0) + __uint_as_float((unsigned)f2));
        bf[1] = 1.0f / (__uint_as_float((unsigned)(f0 >> 32)) + __uint_as_float((unsigned)(f2 >> 32)));
        bf[2] = 1.0f / (__uint_as_float((unsigned)f1) + __uint_as_float((unsigned)f3));
        bf[3] = 1.0f / (__uint_as_float((unsigned)(f1 >> 32)) + __uint_as_float((unsigned)(f3 >> 32)));
    }

    // P,R over this thread's 4 cols; reduce across the 4 threads per A-block
    float Pl[16], Rl[16];
#pragma unroll
    for (int i = 0; i < 16; ++i) {
        Pl[i] = -(C[i][0] + C[i][1] + C[i][2] + C[i][3]);  // C = -Cl
        Rl[i] = aL[i] * (E[i][0] * bf[0] + E[i][1] * bf[1] +
                         E[i][2] * bf[2] + E[i][3] * bf[3]);
    }
#pragma unroll
    for (int m = 1; m < 4; m <<= 1)
#pragma unroll
        for (int i = 0; i < 16; ++i) {
            Pl[i] += __shfl_xor(Pl[i], m, 64);
            Rl[i] += __shfl_xor(Rl[i], m, 64);
        }
    if ((tid & 3) == 0) {
        int A = tid >> 2;
#pragma unroll
        for (int i = 0; i < 16; ++i) { Ps[i][A] = Pl[i]; Rs[i][A] = Rl[i]; }
    }
    __syncthreads();

    // G partial (this WG's 16 k-rows) -> atomicAdd into zeroed d_out
    float Rk[16];
#pragma unroll
    for (int k = 0; k < 16; ++k) Rk[k] = Rs[k][tid & 63];  // B = o&63 = tid&63
    const float sc = 1.0f / (256.0f * 1024.0f);
    float tsum = 0.0f;
#pragma unroll
    for (int q = 0; q < 16; ++q) {
        int o = tid + 256 * q;
        int A = o >> 6, B = o & 63;
        float acc = 0.0f;
#pragma unroll
        for (int k = 0; k < 16; ++k) acc += Ps[k][A] * Rk[k];
        float val = acc * sc;
        atomicAdd(out + o, val);
        if (A == B) tsum += val;
    }
#pragma unroll
    for (int m = 1; m < 64; m <<= 1) tsum += __shfl_xor(tsum, m, 64);
    if (lane == 0) atomicAdd(out + 4096, tsum);
}

// ---------------------------------------------------------------------------
extern "C" void kernel_launch(void* const* d_in, const int* in_sizes, int n_in,
                              void* d_out, int out_size, void* d_ws, size_t ws_size,
                              hipStream_t stream) {
    const float* X = (const float*)d_in[0];  // t_prob [1024,512]
    const float* Y = (const float*)d_in[1];  // v_prob [1024,512]
    float* out = (float*)d_out;              // [64*64 + 1]
    float* ws  = (float*)d_ws;

    // zero cvec + barrier counters (ws poisoned each call), zero d_out
    (void)hipMemsetAsync((char*)d_ws + (size_t)CVEC_OFF * 4, 0,
                         (3 * NREP * 1024 + 32) * 4, stream);
    (void)hipMemsetAsync(d_out, 0, (size_t)out_size * 4, stream);

    k_gemm<<<dim3(16, 16), 256, 0, stream>>>(X, Y, ws);
    k_ipot<<<NWG, TPB, 0, stream>>>(ws, out);
}

// Round 5
// 334.238 us; speedup vs baseline: 7.2374x; 1.3680x over previous
//
#include <hip/hip_runtime.h>
#include <math.h>

// ---------------------------------------------------------------------------
// IPOT on MI355X — round 5.
// Math (exact, verified absmax 0.0 in R1/R2/R4):
//   Cl = -C;  M_t = exp((t+1)*Cl)
//   row:  r_i = sum_j M_t(i,j) s_j ; a = 1/(n r)
//   col:  c_j = sum_i M_t(i,j) a_i ; b = 1/c (2^10 inj); s' = b^2/b_prev/1024
//   final G(A,B) = (1/(256*1024)) sum_k P(k,A) R(k,B)
// R5 (R4's residual = serial chain latency, not tx throughput):
//   - NWG=32 x 256 thr, thread owns 8 rows x 16 cols: C[128]+E[128] VGPR,
//     launch_bounds(256,1) -> 1 wave/SIMD, ~330 VGPR, no spill.
//   - NREP=4: same-address atomicAdd chain 32 -> 8.
//   - No separate grid barrier: readers poll 4 group counters (data-poll);
//     sync = adds -> __syncthreads (vmcnt drain) -> 1 counter inc -> poll.
//   - E_{t+1} recomputed AFTER the adds (overlaps atomic chain / WG skew).
// ---------------------------------------------------------------------------

#define NWG 32
#define TPB 256
#define NIT 50
#define NREP 4

typedef unsigned long long ull;

// ws offsets in floats
constexpr int CL_OFF   = 0;                           // -C [1024*1024]
constexpr int CVEC_OFF = 1024 * 1024;                 // [3][NREP][1024]
constexpr int CNT_OFF  = CVEC_OFF + 3 * NREP * 1024;  // 4 group counters (pad 16)
// total ~ 4.05 MB

// ---------------- C = 1 - xhat yhat^T (norms fused) ; Cl = -C ---------------
__global__ __launch_bounds__(256) void k_gemm(const float* __restrict__ X,
                                              const float* __restrict__ Y,
                                              float* __restrict__ ws) {
    __shared__ float As[32][68];
    __shared__ float Bs[32][68];
    __shared__ float nX[64], nY[64];
    float* Cl = ws + CL_OFF;

    int tid = threadIdx.x;
    int tx = tid & 15, ty = tid >> 4;
    int bx = blockIdx.x, by = blockIdx.y;
    int lr0 = tid >> 3;          // 0..31
    int kq  = (tid & 7) * 4;     // 0..28

    float acc[4][4] = {};
    float sx0 = 0.f, sx1 = 0.f, sy0 = 0.f, sy1 = 0.f;
    for (int k0 = 0; k0 < 512; k0 += 32) {
        float4 xa = *(const float4*)(X + (size_t)(by * 64 + lr0) * 512 + k0 + kq);
        float4 xb = *(const float4*)(X + (size_t)(by * 64 + lr0 + 32) * 512 + k0 + kq);
        float4 ya = *(const float4*)(Y + (size_t)(bx * 64 + lr0) * 512 + k0 + kq);
        float4 yb = *(const float4*)(Y + (size_t)(bx * 64 + lr0 + 32) * 512 + k0 + kq);
        sx0 += xa.x * xa.x + xa.y * xa.y + xa.z * xa.z + xa.w * xa.w;
        sx1 += xb.x * xb.x + xb.y * xb.y + xb.z * xb.z + xb.w * xb.w;
        sy0 += ya.x * ya.x + ya.y * ya.y + ya.z * ya.z + ya.w * ya.w;
        sy1 += yb.x * yb.x + yb.y * yb.y + yb.z * yb.z + yb.w * yb.w;
        As[kq + 0][lr0] = xa.x; As[kq + 1][lr0] = xa.y;
        As[kq + 2][lr0] = xa.z; As[kq + 3][lr0] = xa.w;
        As[kq + 0][lr0 + 32] = xb.x; As[kq + 1][lr0 + 32] = xb.y;
        As[kq + 2][lr0 + 32] = xb.z; As[kq + 3][lr0 + 32] = xb.w;
        Bs[kq + 0][lr0] = ya.x; Bs[kq + 1][lr0] = ya.y;
        Bs[kq + 2][lr0] = ya.z; Bs[kq + 3][lr0] = ya.w;
        Bs[kq + 0][lr0 + 32] = yb.x; Bs[kq + 1][lr0 + 32] = yb.y;
        Bs[kq + 2][lr0 + 32] = yb.z; Bs[kq + 3][lr0 + 32] = yb.w;
        __syncthreads();
#pragma unroll
        for (int kk = 0; kk < 32; ++kk) {
            float4 a4 = *(const float4*)&As[kk][4 * ty];
            float4 b4 = *(const float4*)&Bs[kk][4 * tx];
            float av[4] = {a4.x, a4.y, a4.z, a4.w};
            float bv[4] = {b4.x, b4.y, b4.z, b4.w};
#pragma unroll
            for (int r = 0; r < 4; ++r)
#pragma unroll
                for (int q = 0; q < 4; ++q) acc[r][q] += av[r] * bv[q];
        }
        __syncthreads();
    }
#pragma unroll
    for (int m = 1; m < 8; m <<= 1) {
        sx0 += __shfl_xor(sx0, m, 64);
        sx1 += __shfl_xor(sx1, m, 64);
        sy0 += __shfl_xor(sy0, m, 64);
        sy1 += __shfl_xor(sy1, m, 64);
    }
    if ((tid & 7) == 0) {
        nX[lr0] = sx0; nX[lr0 + 32] = sx1;
        nY[lr0] = sy0; nY[lr0 + 32] = sy1;
    }
    __syncthreads();

    int i0 = by * 64 + 4 * ty, j0 = bx * 64 + 4 * tx;
    float vy[4];
#pragma unroll
    for (int q = 0; q < 4; ++q) vy[q] = 1.0f / sqrtf(nY[4 * tx + q]);
#pragma unroll
    for (int r = 0; r < 4; ++r) {
        float vx = 1.0f / sqrtf(nX[4 * ty + r]);
        float4 o;
        o.x = acc[r][0] * vx * vy[0] - 1.0f;  // Cl = dot - 1 = -C
        o.y = acc[r][1] * vx * vy[1] - 1.0f;
        o.z = acc[r][2] * vx * vy[2] - 1.0f;
        o.w = acc[r][3] * vx * vy[3] - 1.0f;
        *(float4*)(Cl + (size_t)(i0 + r) * 1024 + j0) = o;
    }
}

// ---------------------- persistent IPOT iteration --------------------------
__global__ __launch_bounds__(256, 1) void k_ipot(float* __restrict__ ws,
                                                 float* __restrict__ out) {
    __shared__ float sL[1024];       // s (loop) / b (epilogue)
    __shared__ float aL[32];
    __shared__ float buf[4 * 1024];  // colp[4][1024]; epilogue Ps[0..2047]+Rs[2048..]
    __shared__ float twv[4];

    const int g = blockIdx.x, tid = threadIdx.x;
    const int rs = tid >> 6, lane = tid & 63;  // wave id / lane
    float* Cl   = ws + CL_OFF;
    float* cvec = ws + CVEC_OFF;
    unsigned* grp = (unsigned*)(ws + CNT_OFF);

    // thread owns rows g*32 + rs*8 + i (i<8), cols lane*16 + u (u<16)
    float C[8][16], E[8][16];
#pragma unroll
    for (int i = 0; i < 8; ++i) {
        const float* src = Cl + (size_t)(g * 32 + rs * 8 + i) * 1024 + lane * 16;
#pragma unroll
        for (int q = 0; q < 4; ++q) {
            float4 c = *(const float4*)(src + 4 * q);
            C[i][4 * q + 0] = c.x; C[i][4 * q + 1] = c.y;
            C[i][4 * q + 2] = c.z; C[i][4 * q + 3] = c.w;
        }
    }
#pragma unroll
    for (int i = 0; i < 8; ++i)
#pragma unroll
        for (int u = 0; u < 16; ++u) E[i][u] = __expf(C[i][u]);  // round 0

    float bv[4] = {1.0f, 1.0f, 1.0f, 1.0f};

    for (int t = 0; t < NIT; ++t) {
        if (t == 0) {
            *(float4*)&sL[4 * tid] =
                make_float4(1/1024.f, 1/1024.f, 1/1024.f, 1/1024.f);
        } else {
            if (tid == 0) {  // poll: round t-1 adds complete everywhere
                unsigned tgt = (unsigned)t * 8u;
                long gd = 0;
                while (__hip_atomic_load(&grp[0], __ATOMIC_RELAXED, __HIP_MEMORY_SCOPE_AGENT) < tgt ||
                       __hip_atomic_load(&grp[1], __ATOMIC_RELAXED, __HIP_MEMORY_SCOPE_AGENT) < tgt ||
                       __hip_atomic_load(&grp[2], __ATOMIC_RELAXED, __HIP_MEMORY_SCOPE_AGENT) < tgt ||
                       __hip_atomic_load(&grp[3], __ATOMIC_RELAXED, __HIP_MEMORY_SCOPE_AGENT) < tgt) {
                    __builtin_amdgcn_s_sleep(1);
                    if (++gd > 2000000) break;  // anti-hang bailout
                }
            }
            __syncthreads();
            // readback this thread's 4 cols from buffer (t-1)%3 across 4 reps
            const ull* rb = (const ull*)(cvec + ((t + 2) % 3) * (NREP * 1024)) + 2 * tid;
            ull u00 = __hip_atomic_load(rb + 0 * 512,     __ATOMIC_RELAXED, __HIP_MEMORY_SCOPE_AGENT);
            ull u01 = __hip_atomic_load(rb + 0 * 512 + 1, __ATOMIC_RELAXED, __HIP_MEMORY_SCOPE_AGENT);
            ull u10 = __hip_atomic_load(rb + 1 * 512,     __ATOMIC_RELAXED, __HIP_MEMORY_SCOPE_AGENT);
            ull u11 = __hip_atomic_load(rb + 1 * 512 + 1, __ATOMIC_RELAXED, __HIP_MEMORY_SCOPE_AGENT);
            ull u20 = __hip_atomic_load(rb + 2 * 512,     __ATOMIC_RELAXED, __HIP_MEMORY_SCOPE_AGENT);
            ull u21 = __hip_atomic_load(rb + 2 * 512 + 1, __ATOMIC_RELAXED, __HIP_MEMORY_SCOPE_AGENT);
            ull u30 = __hip_atomic_load(rb + 3 * 512,     __ATOMIC_RELAXED, __HIP_MEMORY_SCOPE_AGENT);
            ull u31 = __hip_atomic_load(rb + 3 * 512 + 1, __ATOMIC_RELAXED, __HIP_MEMORY_SCOPE_AGENT);
            if (t >= 2 && tid < 64) {  // zero buffer (t+1)%3 (read at t-1, all done)
                ull* zb = (ull*)(cvec + ((t + 1) % 3) * (NREP * 1024)) + g * 64 + tid;
                __hip_atomic_store(zb, 0ull, __ATOMIC_RELAXED, __HIP_MEMORY_SCOPE_AGENT);
            }
            float c0 = __uint_as_float((unsigned)u00) + __uint_as_float((unsigned)u10) +
                       __uint_as_float((unsigned)u20) + __uint_as_float((unsigned)u30);
            float c1 = __uint_as_float((unsigned)(u00 >> 32)) + __uint_as_float((unsigned)(u10 >> 32)) +
                       __uint_as_float((unsigned)(u20 >> 32)) + __uint_as_float((unsigned)(u30 >> 32));
            float c2 = __uint_as_float((unsigned)u01) + __uint_as_float((unsigned)u11) +
                       __uint_as_float((unsigned)u21) + __uint_as_float((unsigned)u31);
            float c3 = __uint_as_float((unsigned)(u01 >> 32)) + __uint_as_float((unsigned)(u11 >> 32)) +
                       __uint_as_float((unsigned)(u21 >> 32)) + __uint_as_float((unsigned)(u31 >> 32));
            float b0 = 1.0f / c0, b1 = 1.0f / c1, b2 = 1.0f / c2, b3 = 1.0f / c3;
            float4 sn;
            sn.x = b0 * b0 / bv[0] * (1.0f / 1024.0f); bv[0] = b0;  // 2^-10 inj
            sn.y = b1 * b1 / bv[1] * (1.0f / 1024.0f); bv[1] = b1;
            sn.z = b2 * b2 / bv[2] * (1.0f / 1024.0f); bv[2] = b2;
            sn.w = b3 * b3 / bv[3] * (1.0f / 1024.0f); bv[3] = b3;
            *(float4*)&sL[4 * tid] = sn;
        }
        __syncthreads();

        // row phase: rp[i] = sum_u E[i][u] * s[lane*16+u]; wave-local reduce
        float sv[16];
#pragma unroll
        for (int q = 0; q < 4; ++q) {
            float4 s4 = *(const float4*)&sL[lane * 16 + 4 * q];
            sv[4 * q + 0] = s4.x; sv[4 * q + 1] = s4.y;
            sv[4 * q + 2] = s4.z; sv[4 * q + 3] = s4.w;
        }
        float rp[8];
#pragma unroll
        for (int i = 0; i < 8; ++i) {
            float a = 0.0f;
#pragma unroll
            for (int u = 0; u < 16; ++u) a += E[i][u] * sv[u];
            rp[i] = a;
        }
#pragma unroll
        for (int m = 1; m < 64; m <<= 1)
#pragma unroll
            for (int i = 0; i < 8; ++i) rp[i] += __shfl_xor(rp[i], m, 64);
        if (lane == 0) {
#pragma unroll
            for (int i = 0; i < 8; ++i)
                aL[rs * 8 + i] = 1.0f / (1024.0f * rp[i]);
        }
        __syncthreads();

        // col phase: partials over this wave's 8 rows for its 16 cols
        float av[8];
#pragma unroll
        for (int i = 0; i < 8; ++i) av[i] = aL[rs * 8 + i];
        float cp[16];
#pragma unroll
        for (int u = 0; u < 16; ++u) {
            float a = 0.0f;
#pragma unroll
            for (int i = 0; i < 8; ++i) a += E[i][u] * av[i];
            cp[u] = a;
        }
#pragma unroll
        for (int q = 0; q < 4; ++q)
            *(float4*)&buf[rs * 1024 + lane * 16 + 4 * q] =
                make_float4(cp[4*q], cp[4*q+1], cp[4*q+2], cp[4*q+3]);
        __syncthreads();

        // owner (4 cols/thread): sum 4 wave-partials, atomicAdd to replica g&3
        float4 t0 = *(const float4*)&buf[0 * 1024 + 4 * tid];
        float4 t1 = *(const float4*)&buf[1 * 1024 + 4 * tid];
        float4 t2 = *(const float4*)&buf[2 * 1024 + 4 * tid];
        float4 t3 = *(const float4*)&buf[3 * 1024 + 4 * tid];
        float* wb = cvec + (t % 3) * (NREP * 1024) + (g & 3) * 1024 + 4 * tid;
        atomicAdd(wb + 0, t0.x + t1.x + t2.x + t3.x);
        atomicAdd(wb + 1, t0.y + t1.y + t2.y + t3.y);
        atomicAdd(wb + 2, t0.z + t1.z + t2.z + t3.z);
        atomicAdd(wb + 3, t0.w + t1.w + t2.w + t3.w);
        __syncthreads();  // per-thread vmcnt(0) drain: all adds at LLC
        if (tid == 0)
            __hip_atomic_fetch_add(&grp[g >> 3], 1u, __ATOMIC_RELAXED,
                                   __HIP_MEMORY_SCOPE_AGENT);

        // recompute E for next round (overlaps atomic chain / WG skew)
        if (t < NIT - 1) {
            const float kf = (float)(t + 2);
#pragma unroll
            for (int i = 0; i < 8; ++i)
#pragma unroll
                for (int u = 0; u < 16; ++u) E[i][u] = __expf(kf * C[i][u]);
        }
    }

    // ------------- epilogue: E = exp(50*Cl), aL = round-49 a ----------------
    if (tid == 0) {
        unsigned tgt = (unsigned)NIT * 8u;
        long gd = 0;
        while (__hip_atomic_load(&grp[0], __ATOMIC_RELAXED, __HIP_MEMORY_SCOPE_AGENT) < tgt ||
               __hip_atomic_load(&grp[1], __ATOMIC_RELAXED, __HIP_MEMORY_SCOPE_AGENT) < tgt ||
               __hip_atomic_load(&grp[2], __ATOMIC_RELAXED, __HIP_MEMORY_SCOPE_AGENT) < tgt ||
               __hip_atomic_load(&grp[3], __ATOMIC_RELAXED, __HIP_MEMORY_SCOPE_AGENT) < tgt) {
            __builtin_amdgcn_s_sleep(1);
            if (++gd > 2000000) break;
        }
    }
    __syncthreads();
    {   // final b for this thread's 4 cols -> sL (as bArr)
        const ull* rb = (const ull*)(cvec + ((NIT - 1) % 3) * (NREP * 1024)) + 2 * tid;
        ull u00 = __hip_atomic_load(rb + 0 * 512,     __ATOMIC_RELAXED, __HIP_MEMORY_SCOPE_AGENT);
        ull u01 = __hip_atomic_load(rb + 0 * 512 + 1, __ATOMIC_RELAXED, __HIP_MEMORY_SCOPE_AGENT);
        ull u10 = __hip_atomic_load(rb + 1 * 512,     __ATOMIC_RELAXED, __HIP_MEMORY_SCOPE_AGENT);
        ull u11 = __hip_atomic_load(rb + 1 * 512 + 1, __ATOMIC_RELAXED, __HIP_MEMORY_SCOPE_AGENT);
        ull u20 = __hip_atomic_load(rb + 2 * 512,     __ATOMIC_RELAXED, __HIP_MEMORY_SCOPE_AGENT);
        ull u21 = __hip_atomic_load(rb + 2 * 512 + 1, __ATOMIC_RELAXED, __HIP_MEMORY_SCOPE_AGENT);
        ull u30 = __hip_atomic_load(rb + 3 * 512,     __ATOMIC_RELAXED, __HIP_MEMORY_SCOPE_AGENT);
        ull u31 = __hip_atomic_load(rb + 3 * 512 + 1, __ATOMIC_RELAXED, __HIP_MEMORY_SCOPE_AGENT);
        float4 bb;
        bb.x = 1.0f / (__uint_as_float((unsigned)u00) + __uint_as_float((unsigned)u10) +
                       __uint_as_float((unsigned)u20) + __uint_as_float((unsigned)u30));
        bb.y = 1.0f / (__uint_as_float((unsigned)(u00 >> 32)) + __uint_as_float((unsigned)(u10 >> 32)) +
                       __uint_as_float((unsigned)(u20 >> 32)) + __uint_as_float((unsigned)(u30 >> 32)));
        bb.z = 1.0f / (__uint_as_float((unsigned)u01) + __uint_as_float((unsigned)u11) +
                       __uint_as_float((unsigned)u21) + __uint_as_float((unsigned)u31));
        bb.w = 1.0f / (__uint_as_float((unsigned)(u01 >> 32)) + __uint_as_float((unsigned)(u11 >> 32)) +
                       __uint_as_float((unsigned)(u21 >> 32)) + __uint_as_float((unsigned)(u31 >> 32)));
        *(float4*)&sL[4 * tid] = bb;
    }
    __syncthreads();

    // P(k,A=lane) and R(k,B=lane) for this thread's 8 rows (A-block == lane)
    float* Ps = buf;          // [32][64]
    float* Rs = buf + 2048;   // [32][64]
    float bl[16];
#pragma unroll
    for (int q = 0; q < 4; ++q) {
        float4 b4 = *(const float4*)&sL[lane * 16 + 4 * q];
        bl[4 * q + 0] = b4.x; bl[4 * q + 1] = b4.y;
        bl[4 * q + 2] = b4.z; bl[4 * q + 3] = b4.w;
    }
#pragma unroll
    for (int i = 0; i < 8; ++i) {
        float p = 0.0f, r = 0.0f;
#pragma unroll
        for (int u = 0; u < 16; ++u) {
            p += C[i][u];
            r += E[i][u] * bl[u];
        }
        Ps[(rs * 8 + i) * 64 + lane] = -p;              // C = -Cl
        Rs[(rs * 8 + i) * 64 + lane] = aL[rs * 8 + i] * r;
    }
    __syncthreads();

    // G partial (this WG's 32 k-rows) -> atomicAdd into zeroed d_out
    float Rk[32];
#pragma unroll
    for (int k = 0; k < 32; ++k) Rk[k] = Rs[k * 64 + lane];  // B = lane
    const float sc = 1.0f / (256.0f * 1024.0f);
    float tsum = 0.0f;
#pragma unroll
    for (int q = 0; q < 16; ++q) {
        int o = tid + 256 * q;
        int A = o >> 6;  // = 4*q + rs
        float acc = 0.0f;
#pragma unroll
        for (int k = 0; k < 32; ++k) acc += Ps[k * 64 + A] * Rk[k];
        float val = acc * sc;
        atomicAdd(out + o, val);
        if (A == lane) tsum += val;
    }
#pragma unroll
    for (int m = 1; m < 64; m <<= 1) tsum += __shfl_xor(tsum, m, 64);
    if (lane == 0) twv[rs] = tsum;
    __syncthreads();
    if (tid == 0) atomicAdd(out + 4096, twv[0] + twv[1] + twv[2] + twv[3]);
}

// ---------------------------------------------------------------------------
extern "C" void kernel_launch(void* const* d_in, const int* in_sizes, int n_in,
                              void* d_out, int out_size, void* d_ws, size_t ws_size,
                              hipStream_t stream) {
    const float* X = (const float*)d_in[0];  // t_prob [1024,512]
    const float* Y = (const float*)d_in[1];  // v_prob [1024,512]
    float* out = (float*)d_out;              // [64*64 + 1]
    float* ws  = (float*)d_ws;

    // zero cvec + counters (ws poisoned each call), zero d_out
    (void)hipMemsetAsync((char*)d_ws + (size_t)CVEC_OFF * 4, 0,
                         (3 * NREP * 1024 + 16) * 4, stream);
    (void)hipMemsetAsync(d_out, 0, (size_t)out_size * 4, stream);

    k_gemm<<<dim3(16, 16), 256, 0, stream>>>(X, Y, ws);
    k_ipot<<<NWG, TPB, 0, stream>>>(ws, out);
}